// Round 11
// baseline (62.471 us; speedup 1.0000x reference)
//
#include <hip/hip_runtime.h>

// Problem constants (from reference setup_inputs)
#define BB 4096   // batch
#define SS 256    // sequence length
#define FF 64     // features
#define GG 9      // 3*U gate width

#define NEG_LOG2E -1.4426950408889634f
#define TWO_LOG2E  2.8853900817779268f

typedef float f2 __attribute__((ext_vector_type(2)));

#if __has_builtin(__builtin_amdgcn_exp2f)
__device__ __forceinline__ float fast_exp2(float x) { return __builtin_amdgcn_exp2f(x); }
#else
__device__ __forceinline__ float fast_exp2(float x) { return exp2f(x); }
#endif
#if __has_builtin(__builtin_amdgcn_rcpf)
__device__ __forceinline__ float fast_rcp(float x) { return __builtin_amdgcn_rcpf(x); }
#else
__device__ __forceinline__ float fast_rcp(float x) { return 1.0f / x; }
#endif

// DPP helper: quad_perm (CTRL<0x100) and row ops (row_ror:N = 0x120+N).
template <int CTRL>
__device__ __forceinline__ float dpp_f(float v) {
  return __int_as_float(
      __builtin_amdgcn_mov_dpp(__float_as_int(v), CTRL, 0xF, 0xF, true));
}

// -----------------------------------------------------------------------------
// Fully fused GRU — R11 = R10 (61us) + source-level proj/gate software pipeline.
// R10 post-mortem: ~570cy/step vs ~196cy issue -> ~370cy of DEPENDENCY stalls
// (serial gate chain; next step's independent proj sits after it in program
// order). R11 staggers: proj(s+1) is emitted BEFORE gate(s), so the scheduler
// has ~56 independent VALU instrs to fill every gate-chain bubble. Pipeline
// state = 3 floats/stage (24 VGPR total) -- no R6-style allocator collapse.
// Also: recurrent bias for z/r gates folded into the lane input bias (exact).
// -----------------------------------------------------------------------------
__global__ __launch_bounds__(64, 1) void fused_gru_kernel(
    const float* __restrict__ x,           // [B,S,F]
    const float* __restrict__ kernel_w,    // [F,9]
    const float* __restrict__ rec_kernel,  // [3,9]
    const float* __restrict__ bias,        // [2,9]
    const float* __restrict__ dense_w,     // [3,10]
    const float* __restrict__ dense_b,     // [10]
    float* __restrict__ out)               // [B,10]
{
  const int lane = threadIdx.x;        // 0..63
  const int fl   = lane & 15;          // feature-slot within the chain's row
  const int u    = lane & 3;           // gate-unit role within the quad
  const int uc   = (u < 3) ? u : 2;    // lane u==3: clamp unit role (benign)
  const int c    = blockIdx.x * 4 + (lane >> 4);   // chain (batch) id

  // ---- input-projection weights for this lane's 4 features (pre-scaled)
  f2 w01[4], w23[4], w45[4], w67[4];
  float w8[4];
#pragma unroll
  for (int e = 0; e < 4; ++e) {
    const float* kw = kernel_w + (fl * 4 + e) * GG;
    w01[e] = (f2){kw[0] * NEG_LOG2E, kw[1] * NEG_LOG2E};
    w23[e] = (f2){kw[2] * NEG_LOG2E, kw[3] * NEG_LOG2E};
    w45[e] = (f2){kw[4] * NEG_LOG2E, kw[5] * NEG_LOG2E};
    w67[e] = (f2){kw[6] * TWO_LOG2E, kw[7] * TWO_LOG2E};
    w8[e]  = kw[8] * TWO_LOG2E;
  }

  // input bias + (for z/r gates) recurrent bias folded in, pre-scaled and
  // SIXTEENTH'd (16-lane reduce restores exactly 1x; fold is algebraically
  // exact since sigmoid arg = x·k + b0 + h·W + b1 is one flat sum).
  const float Q = 0.0625f;
  const f2 b01q = {(bias[0] + bias[GG + 0]) * NEG_LOG2E * Q,
                   (bias[1] + bias[GG + 1]) * NEG_LOG2E * Q};
  const f2 b23q = {(bias[2] + bias[GG + 2]) * NEG_LOG2E * Q,
                   (bias[3] + bias[GG + 3]) * NEG_LOG2E * Q};
  const f2 b45q = {(bias[4] + bias[GG + 4]) * NEG_LOG2E * Q,
                   (bias[5] + bias[GG + 5]) * NEG_LOG2E * Q};
  const f2 b67q = {bias[6] * TWO_LOG2E * Q, bias[7] * TWO_LOG2E * Q};
  const float b8q = bias[8] * TWO_LOG2E * Q;

  // recurrent weights for this lane's unit (pre-scaled); only the h-gate's
  // recurrent bias stays separate (it sits inside the r-multiplied term).
  float wz[3], wr[3], wh[3];
#pragma unroll
  for (int hh = 0; hh < 3; ++hh) {
    wz[hh] = rec_kernel[hh * GG + uc]     * NEG_LOG2E;
    wr[hh] = rec_kernel[hh * GG + 3 + uc] * NEG_LOG2E;
    wh[hh] = rec_kernel[hh * GG + 6 + uc] * TWO_LOG2E;
  }
  const float rbh = bias[GG + 6 + uc] * TWO_LOG2E;

  float h0 = 0.0f, h1 = 0.0f, h2 = 0.0f, hprev = 0.0f;

  // per-lane x pointer: row (c,s) = 16 float4s; this lane reads float4 #fl.
  const float4* pc = reinterpret_cast<const float4*>(x) + (size_t)c * SS * 16 + fl;

  // depth-8 register ring (32 VGPRs), named buffers, static indexing
  float4 X0, X1, X2, X3, X4, X5, X6, X7;

  // h-independent phase: proj FMAs + 16-lane DPP reduce + role select.
  auto proj = [&](const float4 v, float& oaz, float& oar, float& osh) {
    f2 a01 = b01q, a23 = b23q, a45 = b45q, a67 = b67q;
    float a8 = b8q;
    a01 = v.x * w01[0] + a01; a23 = v.x * w23[0] + a23;
    a45 = v.x * w45[0] + a45; a67 = v.x * w67[0] + a67;
    a8 = fmaf(v.x, w8[0], a8);
    a01 = v.y * w01[1] + a01; a23 = v.y * w23[1] + a23;
    a45 = v.y * w45[1] + a45; a67 = v.y * w67[1] + a67;
    a8 = fmaf(v.y, w8[1], a8);
    a01 = v.z * w01[2] + a01; a23 = v.z * w23[2] + a23;
    a45 = v.z * w45[2] + a45; a67 = v.z * w67[2] + a67;
    a8 = fmaf(v.z, w8[2], a8);
    a01 = v.w * w01[3] + a01; a23 = v.w * w23[3] + a23;
    a45 = v.w * w45[3] + a45; a67 = v.w * w67[3] + a67;
    a8 = fmaf(v.w, w8[3], a8);

    // 16-lane reduce: quad_perm xor1, xor2; row_ror:4 (0x124), row_ror:8
    // (0x128) rotate-accumulate across quads. 36 single-instr DPP-adds.
    float s0 = a01.x, s1 = a01.y, s2 = a23.x, s3 = a23.y, s4 = a45.x,
          s5 = a45.y, s6 = a67.x, s7 = a67.y, s8 = a8;
    s0 += dpp_f<0xB1>(s0); s1 += dpp_f<0xB1>(s1); s2 += dpp_f<0xB1>(s2);
    s3 += dpp_f<0xB1>(s3); s4 += dpp_f<0xB1>(s4); s5 += dpp_f<0xB1>(s5);
    s6 += dpp_f<0xB1>(s6); s7 += dpp_f<0xB1>(s7); s8 += dpp_f<0xB1>(s8);
    s0 += dpp_f<0x4E>(s0); s1 += dpp_f<0x4E>(s1); s2 += dpp_f<0x4E>(s2);
    s3 += dpp_f<0x4E>(s3); s4 += dpp_f<0x4E>(s4); s5 += dpp_f<0x4E>(s5);
    s6 += dpp_f<0x4E>(s6); s7 += dpp_f<0x4E>(s7); s8 += dpp_f<0x4E>(s8);
    s0 += dpp_f<0x124>(s0); s1 += dpp_f<0x124>(s1); s2 += dpp_f<0x124>(s2);
    s3 += dpp_f<0x124>(s3); s4 += dpp_f<0x124>(s4); s5 += dpp_f<0x124>(s5);
    s6 += dpp_f<0x124>(s6); s7 += dpp_f<0x124>(s7); s8 += dpp_f<0x124>(s8);
    s0 += dpp_f<0x128>(s0); s1 += dpp_f<0x128>(s1); s2 += dpp_f<0x128>(s2);
    s3 += dpp_f<0x128>(s3); s4 += dpp_f<0x128>(s4); s5 += dpp_f<0x128>(s5);
    s6 += dpp_f<0x128>(s6); s7 += dpp_f<0x128>(s7); s8 += dpp_f<0x128>(s8);

    oaz = (u == 0) ? s0 : ((u == 1) ? s1 : s2);  // z arg (b1 already folded)
    oar = (u == 0) ? s3 : ((u == 1) ? s4 : s5);  // r arg (b1 already folded)
    osh = (u == 0) ? s6 : ((u == 1) ? s7 : s8);  // h x-side arg
  };

  // serial phase: the h-dependent gate chain (absmax-0 verified math)
  auto gate = [&](float az, float ar, float sh) {
    const float iz = fmaf(h2, wz[2], fmaf(h1, wz[1], fmaf(h0, wz[0], az)));
    const float ir = fmaf(h2, wr[2], fmaf(h1, wr[1], fmaf(h0, wr[0], ar)));
    const float ih = fmaf(h2, wh[2], fmaf(h1, wh[1], fmaf(h0, wh[0], rbh)));
    const float z = fast_rcp(1.0f + fast_exp2(iz));
    const float r = fast_rcp(1.0f + fast_exp2(ir));
    const float t = fmaf(-2.0f, fast_rcp(1.0f + fast_exp2(fmaf(r, ih, sh))), 1.0f);
    const float hn = fmaf(z, hprev - t, t);
    hprev = hn;
    h0 = dpp_f<0x00>(hn);   // quad_perm [0,0,0,0]
    h1 = dpp_f<0x55>(hn);   // quad_perm [1,1,1,1]
    h2 = dpp_f<0xAA>(hn);   // quad_perm [2,2,2,2]
  };

  // branchless prefetch-index clamp: tail re-reads step SS-1 (L1-hit, free)
  auto pf = [&](int sn) -> float4 {
    sn = (sn < SS) ? sn : (SS - 1);
    return pc[(size_t)sn * 16];
  };

  X0 = pf(0); X1 = pf(1); X2 = pf(2); X3 = pf(3);
  X4 = pf(4); X5 = pf(5); X6 = pf(6); X7 = pf(7);

  float az0, ar0, sh0, az1, ar1, sh1, az2, ar2, sh2, az3, ar3, sh3;
  float az4, ar4, sh4, az5, ar5, sh5, az6, ar6, sh6, az7, ar7, sh7;

  // prologue: proj of step 0
  proj(X0, az0, ar0, sh0); X0 = pf(8);

  // Invariant at loop top: (az0,ar0,sh0) = proj(step sg); X1..X7 hold steps
  // sg+1..sg+7; X0 holds step sg+8. Each line issues the NEXT step's proj
  // before the current step's gate -> scheduler fills gate stalls with proj.
  for (int sg = 0; sg < SS; sg += 8) {
    proj(X1, az1, ar1, sh1); X1 = pf(sg + 9);  gate(az0, ar0, sh0);
    proj(X2, az2, ar2, sh2); X2 = pf(sg + 10); gate(az1, ar1, sh1);
    proj(X3, az3, ar3, sh3); X3 = pf(sg + 11); gate(az2, ar2, sh2);
    proj(X4, az4, ar4, sh4); X4 = pf(sg + 12); gate(az3, ar3, sh3);
    proj(X5, az5, ar5, sh5); X5 = pf(sg + 13); gate(az4, ar4, sh4);
    proj(X6, az6, ar6, sh6); X6 = pf(sg + 14); gate(az5, ar5, sh5);
    proj(X7, az7, ar7, sh7); X7 = pf(sg + 15); gate(az6, ar6, sh6);
    proj(X0, az0, ar0, sh0); X0 = pf(sg + 16); gate(az7, ar7, sh7);
  }

  // Dense (3 -> 10) + softmax; only quad 0 of each chain row writes.
  if (fl < 4) {
    float lg[10];
#pragma unroll
    for (int j = 0; j < 10; ++j)
      lg[j] = dense_b[j] + h0 * dense_w[j] + h1 * dense_w[10 + j] + h2 * dense_w[20 + j];
    float m = lg[0];
#pragma unroll
    for (int j = 1; j < 10; ++j) m = fmaxf(m, lg[j]);
    float e[10];
    float ssum = 0.0f;
#pragma unroll
    for (int j = 0; j < 10; ++j) {
      e[j] = fast_exp2(1.4426950408889634f * (lg[j] - m));
      ssum += e[j];
    }
    const float inv = fast_rcp(ssum);
#pragma unroll
    for (int j = u; j < 10; j += 4) out[(size_t)c * 10 + j] = e[j] * inv;
  }
}

extern "C" void kernel_launch(void* const* d_in, const int* in_sizes, int n_in,
                              void* d_out, int out_size, void* d_ws, size_t ws_size,
                              hipStream_t stream) {
  const float* x      = (const float*)d_in[0];  // [4096,256,64]
  const float* kern   = (const float*)d_in[1];  // [64,9]
  const float* rkern  = (const float*)d_in[2];  // [3,9]
  const float* bias   = (const float*)d_in[3];  // [2,9]
  const float* dw     = (const float*)d_in[4];  // [3,10]
  const float* db     = (const float*)d_in[5];  // [10]
  float* out = (float*)d_out;

  // 4 chains x 16 lanes per 64-thread block; 1024 blocks -> 1 wave per SIMD
  // on all 1024 SIMDs.
  fused_gru_kernel<<<BB / 4, 64, 0, stream>>>(x, kern, rkern, bias, dw, db, out);
}